// Round 3
// baseline (965.651 us; speedup 1.0000x reference)
//
#include <hip/hip_runtime.h>
#include <cstdint>
#include <cstddef>

// Problem constants
#define LSEQ 2048
#define BB   32
#define DD   1024
#define NLAYERS 4
#define MM   (LSEQ*BB)      // 65536 rows
#define BD   (BB*DD)        // 32768
#define CHUNK 32
#define NCHUNK (LSEQ/CHUNK) // 64

typedef _Float16 f16;
typedef __attribute__((ext_vector_type(8))) _Float16 f16x8;
typedef __attribute__((ext_vector_type(4))) float f32x4;

// ---------------- scan: h[t] = a*h[t-1] + x[t], a = exp(A_log[d]) ----------------

__global__ void scan_pass1(const float* __restrict__ x, const float* __restrict__ Alog,
                           f16* __restrict__ h, float* __restrict__ carry) {
    int tid = blockIdx.x * blockDim.x + threadIdx.x;   // 2M threads
    int bd  = tid & (BD - 1);
    int c   = tid >> 15;                               // chunk id
    float a = expf(Alog[bd & (DD - 1)]);
    size_t base = (size_t)c * CHUNK * BD + bd;
    float hv = 0.f;
#pragma unroll
    for (int i = 0; i < CHUNK; ++i) {
        hv = a * hv + x[base + (size_t)i * BD];
        h[base + (size_t)i * BD] = (f16)hv;
    }
    carry[c * BD + bd] = hv;
}

__global__ void scan_pass2(const float* __restrict__ Alog, float* __restrict__ carry) {
    int bd = blockIdx.x * blockDim.x + threadIdx.x;    // 32768 threads
    float d32 = expf((float)CHUNK * Alog[bd & (DD - 1)]);  // a^CHUNK
    float cin = 0.f;
    for (int c = 0; c < NCHUNK; ++c) {
        float co = carry[c * BD + bd];
        carry[c * BD + bd] = cin;       // exclusive carry-in
        cin = d32 * cin + co;
    }
}

__global__ void scan_pass3(const float* __restrict__ Alog, const float* __restrict__ carry,
                           f16* __restrict__ h) {
    int tid = blockIdx.x * blockDim.x + threadIdx.x;
    int bd  = tid & (BD - 1);
    int c   = tid >> 15;
    float a   = expf(Alog[bd & (DD - 1)]);
    float cin = carry[c * BD + bd];
    size_t base = (size_t)c * CHUNK * BD + bd;
    float p = a;
#pragma unroll
    for (int i = 0; i < CHUNK; ++i) {
        size_t idx = base + (size_t)i * BD;
        float hv = (float)h[idx] + p * cin;
        h[idx] = (f16)hv;
        p *= a;
    }
}

// ---------------- fp32 -> fp16 weight conversion ----------------

__global__ void cvt_w(const float* __restrict__ w, f16* __restrict__ o, int n) {
    int i = (blockIdx.x * blockDim.x + threadIdx.x) * 4;
    if (i + 3 < n) {
        float4 v = *(const float4*)&w[i];
        o[i + 0] = (f16)v.x; o[i + 1] = (f16)v.y;
        o[i + 2] = (f16)v.z; o[i + 3] = (f16)v.w;
    }
}

// ---------------- GEMM + bias + tanh, 256x256 tile, phase-split schedule ----------------
// C[m][n] = tanh(sum_k A[m][k]*W[n][k] + b[n])
// A: [MM][1024] f16 row-major. W: [1024][1024] f16 row-major (K contiguous).
// 512 threads = 8 waves (2M x 4N), wave tile 128x64, mfma 16x16x32 f16.
// BK=32, double-buffered LDS (64 KiB), 2 phases/K-tile, 16 MFMA/phase.
// T4: counted vmcnt(2) at K-tile entry only (loads stay in flight across barriers).
// T2: LDS XOR swizzle chunk ^= ((row>>1)&3) on 64B rows; pre-swizzled global
//     source (gload_lds dest linear, rule #21), same XOR on ds_read.
// T5: setprio(1) around MFMA clusters.
// T1: XCD-chunked bijective blockIdx swizzle (nwg=1024, %8==0).

#define BM 256
#define BN 256
#define BK2 32
#define KK 1024
#define NN 1024
#define NKT (KK / BK2)      // 32 K-tiles

__device__ __forceinline__ void gload_lds16(const void* g, void* l) {
    __builtin_amdgcn_global_load_lds((const __attribute__((address_space(1))) unsigned int*)g,
                                     (__attribute__((address_space(3))) unsigned int*)l,
                                     16, 0, 0);
}

// stage one 256x32 f16 tile (16 KiB) into LDS: 2 x 16B per thread, linear dest,
// inverse-swizzled global source. G = matrix base + tilerow*KK + kt*BK2.
__device__ __forceinline__ void stage_tile(const f16* __restrict__ G, f16* lds, int tid) {
#pragma unroll
    for (int j = 0; j < 2; ++j) {
        int s   = tid + j * 512;            // 16B slot 0..1023
        int row = s >> 2;                   // 0..255
        int c   = (s & 3) ^ ((row >> 1) & 3);
        gload_lds16(G + (size_t)row * KK + c * 8, lds + s * 8);
    }
}

// swizzled fragment read: (row, 16B-chunk) of a [256][32] f16 tile
__device__ __forceinline__ f16x8 rd_swz(const f16* lds, int rloc, int chunk) {
    int c = chunk ^ ((rloc >> 1) & 3);
    return *(const f16x8*)(lds + rloc * 32 + c * 8);
}

__global__ __launch_bounds__(512, 2) void gemm_tanh(const f16* __restrict__ A,
                                                    const f16* __restrict__ W,
                                                    const float* __restrict__ bias,
                                                    f16* __restrict__ C) {
    __shared__ f16 As[2][BM * BK2];   // 2 x 16 KiB
    __shared__ f16 Bs[2][BN * BK2];   // 2 x 16 KiB

    const int tid  = threadIdx.x;
    const int lane = tid & 63;
    const int wid  = tid >> 6;        // 0..7
    const int wr   = wid >> 2;        // 0..1  (M)
    const int wc   = wid & 3;         // 0..3  (N)

    // T1 swizzle
    const int cpx = gridDim.x >> 3;
    const int lin = ((int)blockIdx.x & 7) * cpx + ((int)blockIdx.x >> 3);
    const int tm  = (lin >> 2) * BM;          // 256 M-panels, slow within XCD
    const int tn  = (lin & 3) * BN;           // 4 N-tiles, fast within XCD

    const f16* Ab = A + (size_t)tm * KK;
    const f16* Wb = W + (size_t)tn * KK;

    const int fr = lane & 15;         // fragment row within 16
    const int fc = lane >> 4;         // 16B chunk 0..3 (K dim)

    f32x4 acc[8][4];
#pragma unroll
    for (int i = 0; i < 8; ++i)
#pragma unroll
        for (int j = 0; j < 4; ++j)
            acc[i][j] = (f32x4){0.f, 0.f, 0.f, 0.f};

    // prologue: stage K-tile 0 into buffer 0 (4 loads/thread in flight)
    stage_tile(Ab, &As[0][0], tid);
    stage_tile(Wb, &Bs[0][0], tid);

    for (int kt = 0; kt < NKT; ++kt) {
        const int cur = kt & 1, nxt = cur ^ 1;
        const bool pf = (kt + 1 < NKT);
        const f16* Ac = &As[cur][0];
        const f16* Bc = &Bs[cur][0];

        // ---------- phase 0 (K-tile entry): stage A(next); counted vmcnt; MFMA mh=0
        if (pf) {
            stage_tile(Ab + (size_t)(kt + 1) * BK2, &As[nxt][0], tid);
            asm volatile("s_waitcnt vmcnt(2)" ::: "memory");   // cur's 4 landed, 2 newest in flight
        } else {
            asm volatile("s_waitcnt vmcnt(0)" ::: "memory");   // last tile: drain
        }
        __builtin_amdgcn_s_barrier();
        __builtin_amdgcn_sched_barrier(0);
        {
            f16x8 af[4], bf[4];
#pragma unroll
            for (int i = 0; i < 4; ++i) {
                af[i] = rd_swz(Ac, wr * 128 + i * 16 + fr, fc);
                bf[i] = rd_swz(Bc, wc * 64  + i * 16 + fr, fc);
            }
            __builtin_amdgcn_s_setprio(1);
#pragma unroll
            for (int i = 0; i < 4; ++i)
#pragma unroll
                for (int ni = 0; ni < 4; ++ni)
                    acc[i][ni] = __builtin_amdgcn_mfma_f32_16x16x32_f16(af[i], bf[ni], acc[i][ni], 0, 0, 0);
            __builtin_amdgcn_s_setprio(0);
        }
        __builtin_amdgcn_sched_barrier(0);
        __builtin_amdgcn_s_barrier();
        __builtin_amdgcn_sched_barrier(0);

        // ---------- phase 1: reads mh=1; stage W(next); MFMA mh=1
        {
            f16x8 af[4], bf[4];
#pragma unroll
            for (int i = 0; i < 4; ++i) {
                af[i] = rd_swz(Ac, wr * 128 + 64 + i * 16 + fr, fc);
                bf[i] = rd_swz(Bc, wc * 64       + i * 16 + fr, fc);
            }
            if (pf) stage_tile(Wb + (size_t)(kt + 1) * BK2, &Bs[nxt][0], tid);
            __builtin_amdgcn_s_barrier();
            asm volatile("s_waitcnt lgkmcnt(0)" ::: "memory");  // all reads of cur retired
            __builtin_amdgcn_sched_barrier(0);
            __builtin_amdgcn_s_setprio(1);
#pragma unroll
            for (int i = 0; i < 4; ++i)
#pragma unroll
                for (int ni = 0; ni < 4; ++ni)
                    acc[4 + i][ni] = __builtin_amdgcn_mfma_f32_16x16x32_f16(af[i], bf[ni], acc[4 + i][ni], 0, 0, 0);
            __builtin_amdgcn_s_setprio(0);
        }
        __builtin_amdgcn_sched_barrier(0);
        __builtin_amdgcn_s_barrier();    // after this, next kt may overwrite cur
        __builtin_amdgcn_sched_barrier(0);
    }

    // epilogue: bias + tanh, store f16
#pragma unroll
    for (int ni = 0; ni < 4; ++ni) {
        // bias per output column (hoisted out of mi loop)
        const int c = tn + wc * 64 + ni * 16 + fr;
        const float bv = bias[c];
#pragma unroll
        for (int mi = 0; mi < 8; ++mi) {
            const int r0 = tm + wr * 128 + mi * 16 + (fc << 2);
#pragma unroll
            for (int q = 0; q < 4; ++q) {
                float z = acc[mi][ni][q] + bv;
                C[(size_t)(r0 + q) * NN + c] = (f16)tanhf(z);
            }
        }
    }
}

// ---------------- head: out[m] = sum_d h[m][d]*hw[d] + hb ----------------

__global__ void head_k(const f16* __restrict__ h, const float* __restrict__ hw,
                       const float* __restrict__ hb, float* __restrict__ out) {
    const int row  = blockIdx.x * 4 + (threadIdx.x >> 6);
    const int lane = threadIdx.x & 63;
    const f16* hr = h + (size_t)row * DD;
    float s = 0.f;
#pragma unroll
    for (int j = 0; j < DD / 64; ++j) {
        int d = lane + j * 64;
        s += (float)hr[d] * hw[d];
    }
#pragma unroll
    for (int o = 32; o > 0; o >>= 1) s += __shfl_down(s, o, 64);
    if (lane == 0) out[row] = s + hb[0];
}

// ---------------- launch ----------------

extern "C" void kernel_launch(void* const* d_in, const int* in_sizes, int n_in,
                              void* d_out, int out_size, void* d_ws, size_t ws_size,
                              hipStream_t stream) {
    const float* x    = (const float*)d_in[0];
    const float* Alog = (const float*)d_in[1];
    const float* Wls  = (const float*)d_in[2];
    const float* bls  = (const float*)d_in[3];
    const float* hw   = (const float*)d_in[4];
    const float* hb   = (const float*)d_in[5];
    float* out = (float*)d_out;

    char* ws = (char*)d_ws;
    const size_t hbytes = (size_t)MM * DD * sizeof(f16);   // 128 MiB
    f16* h0 = (f16*)ws;
    f16* h1 = (f16*)(ws + hbytes);
    char* scratch = ws + 2 * hbytes;
    float* carry = (float*)scratch;                         // 8 MiB, scan phase only
    f16*   wf    = (f16*)scratch;                           // 8 MiB, reused after scan

    // 1. scan (chunked, 3 passes)
    scan_pass1<<<(NCHUNK * BD) / 256, 256, 0, stream>>>(x, Alog, h0, carry);
    scan_pass2<<<BD / 256, 256, 0, stream>>>(Alog, carry);
    scan_pass3<<<(NCHUNK * BD) / 256, 256, 0, stream>>>(Alog, carry, h0);

    // 2. weights fp32 -> fp16 (reuses carry region; stream-ordered after pass3)
    cvt_w<<<(NLAYERS * DD * DD / 4) / 256, 256, 0, stream>>>(Wls, wf, NLAYERS * DD * DD);

    // 3. four layers, ping-pong (1-D grid of 1024 blocks, swizzles inside kernel)
    dim3 grid((MM / BM) * (NN / BN)), blk(512);
    gemm_tanh<<<grid, blk, 0, stream>>>(h0, wf + 0 * (DD * DD), bls + 0 * DD, h1);
    gemm_tanh<<<grid, blk, 0, stream>>>(h1, wf + 1 * (DD * DD), bls + 1 * DD, h0);
    gemm_tanh<<<grid, blk, 0, stream>>>(h0, wf + 2 * (DD * DD), bls + 2 * DD, h1);
    gemm_tanh<<<grid, blk, 0, stream>>>(h1, wf + 3 * (DD * DD), bls + 3 * DD, h0);

    // 4. head
    head_k<<<MM / 4, 256, 0, stream>>>(h0, hw, hb, out);
}

// Round 4
// 826.642 us; speedup vs baseline: 1.1682x; 1.1682x over previous
//
#include <hip/hip_runtime.h>
#include <cstdint>
#include <cstddef>

// Problem constants
#define LSEQ 2048
#define BB   32
#define DD   1024
#define NLAYERS 4
#define MM   (LSEQ*BB)      // 65536 rows
#define BD   (BB*DD)        // 32768
#define CHUNK 32
#define NCHUNK (LSEQ/CHUNK) // 64

typedef _Float16 f16;
typedef __attribute__((ext_vector_type(8))) _Float16 f16x8;
typedef __attribute__((ext_vector_type(4))) float f32x4;

// ---------------- scan: h[t] = a*h[t-1] + x[t], a = exp(A_log[d]) ----------------

__global__ void scan_pass1(const float* __restrict__ x, const float* __restrict__ Alog,
                           f16* __restrict__ h, float* __restrict__ carry) {
    int tid = blockIdx.x * blockDim.x + threadIdx.x;   // 2M threads
    int bd  = tid & (BD - 1);
    int c   = tid >> 15;                               // chunk id
    float a = expf(Alog[bd & (DD - 1)]);
    size_t base = (size_t)c * CHUNK * BD + bd;
    float hv = 0.f;
#pragma unroll
    for (int i = 0; i < CHUNK; ++i) {
        hv = a * hv + x[base + (size_t)i * BD];
        h[base + (size_t)i * BD] = (f16)hv;
    }
    carry[c * BD + bd] = hv;
}

__global__ void scan_pass2(const float* __restrict__ Alog, float* __restrict__ carry) {
    int bd = blockIdx.x * blockDim.x + threadIdx.x;    // 32768 threads
    float d32 = expf((float)CHUNK * Alog[bd & (DD - 1)]);  // a^CHUNK
    float cin = 0.f;
    for (int c = 0; c < NCHUNK; ++c) {
        float co = carry[c * BD + bd];
        carry[c * BD + bd] = cin;       // exclusive carry-in
        cin = d32 * cin + co;
    }
}

__global__ void scan_pass3(const float* __restrict__ Alog, const float* __restrict__ carry,
                           f16* __restrict__ h) {
    int tid = blockIdx.x * blockDim.x + threadIdx.x;
    int bd  = tid & (BD - 1);
    int c   = tid >> 15;
    float a   = expf(Alog[bd & (DD - 1)]);
    float cin = carry[c * BD + bd];
    size_t base = (size_t)c * CHUNK * BD + bd;
    float p = a;
#pragma unroll
    for (int i = 0; i < CHUNK; ++i) {
        size_t idx = base + (size_t)i * BD;
        float hv = (float)h[idx] + p * cin;
        h[idx] = (f16)hv;
        p *= a;
    }
}

// ---------------- fp32 -> fp16 weight conversion ----------------

__global__ void cvt_w(const float* __restrict__ w, f16* __restrict__ o, int n) {
    int i = (blockIdx.x * blockDim.x + threadIdx.x) * 4;
    if (i + 3 < n) {
        float4 v = *(const float4*)&w[i];
        o[i + 0] = (f16)v.x; o[i + 1] = (f16)v.y;
        o[i + 2] = (f16)v.z; o[i + 3] = (f16)v.w;
    }
}

// ---------------- GEMM + bias + tanh: m201-geometry 8-phase schedule ----------------
// C[m][n] = tanh(sum_k A[m][k]*W[n][k] + b[n])
// Tile 256x256, BK=64, 2 K-tiles/iter (buf0=even, buf1=odd), 8 phases/iter,
// 16 MFMA (16x16x32 f16) per phase. 512 thr = 8 waves (2M x 4N), wave tile 128x64.
// LDS 128 KiB: As[2][256][64] + Bs[2][256][64] f16.
// Reads front-loaded: ph1/ph2 read buf0 (12 b128 each), ph5/ph6 read buf1.
// Stage ring: buf0 halves(tile 2i+2) @ ph3,4,5,6; buf1 halves(tile 2i+3) @ ph7,8.
// vmcnt(4) @ ph4 (buf1 tile landed before ph5 reads); vmcnt(8) @ ph8 (buf0
// tile landed before next ph1 reads). Last iter: vmcnt(0).
// T2: chunk ^= (row&7) XOR swizzle (8x16B slots/row), inverse-swz global src.
// T5: setprio around MFMA clusters. T1: XCD-chunked block swizzle.

#define BM 256
#define BN 256
#define BK 64
#define KK 1024
#define NN 1024
#define NKTILE (KK / BK)     // 16
#define NITER  (NKTILE / 2)  // 8

__device__ __forceinline__ void gload_lds16(const void* g, void* l) {
    __builtin_amdgcn_global_load_lds((const __attribute__((address_space(1))) unsigned int*)g,
                                     (__attribute__((address_space(3))) unsigned int*)l,
                                     16, 0, 0);
}

// stage one half-tile: 128 rows x 64 f16 = 16 KiB, 2 loads/thread.
// gbase already points at (matrix_base + (tile_row0 + H*128)*KK + kt*64).
__device__ __forceinline__ void stage_half(const f16* __restrict__ gbase, f16* region, int tid) {
#pragma unroll
    for (int j = 0; j < 2; ++j) {
        int s = tid + j * 512;               // 16B slot 0..1023
        int r = s >> 3;                      // local row 0..127
        int c = (s & 7) ^ (r & 7);           // inverse-swizzled source chunk
        gload_lds16(gbase + (size_t)r * KK + c * 8, region + (size_t)s * 8);
    }
}

// swizzled fragment read from a [256][64] f16 tile
__device__ __forceinline__ f16x8 rd(const f16* base, int row, int chunk) {
    int c = chunk ^ (row & 7);
    return *(const f16x8*)(base + row * 64 + c * 8);
}

#define BAR() do { __builtin_amdgcn_sched_barrier(0); __builtin_amdgcn_s_barrier(); \
                   __builtin_amdgcn_sched_barrier(0); } while (0)

__global__ __launch_bounds__(512, 2) void gemm_tanh(const f16* __restrict__ A,
                                                    const f16* __restrict__ W,
                                                    const float* __restrict__ bias,
                                                    f16* __restrict__ C) {
    __shared__ f16 As[2][BM * BK];   // 2 x 32 KiB
    __shared__ f16 Bs[2][BN * BK];   // 2 x 32 KiB

    const int tid  = threadIdx.x;
    const int lane = tid & 63;
    const int wid  = tid >> 6;        // 0..7
    const int wr   = wid >> 2;        // 0..1  (M half)
    const int wc   = wid & 3;         // 0..3  (N quarter)

    // T1: XCD-chunked bijective swizzle (nwg=1024, %8==0)
    const int cpx = gridDim.x >> 3;
    const int lin = ((int)blockIdx.x & 7) * cpx + ((int)blockIdx.x >> 3);
    const int tm  = (lin >> 2) * BM;
    const int tn  = (lin & 3) * BN;

    const f16* Ab = A + (size_t)tm * KK;
    const f16* Wb = W + (size_t)tn * KK;

    const int fr = lane & 15;         // fragment row within 16
    const int fc = lane >> 4;         // 16B k-chunk 0..3 within a 32-k step

    f32x4 acc[8][4];
#pragma unroll
    for (int i = 0; i < 8; ++i)
#pragma unroll
        for (int j = 0; j < 4; ++j)
            acc[i][j] = (f32x4){0.f, 0.f, 0.f, 0.f};

    // prologue: tile0 -> buf0, tile1 -> buf1 (8 halves, 16 loads/thread)
    stage_half(Ab,                              &As[0][0],    tid);
    stage_half(Ab + (size_t)128 * KK,           &As[0][8192], tid);
    stage_half(Wb,                              &Bs[0][0],    tid);
    stage_half(Wb + (size_t)128 * KK,           &Bs[0][8192], tid);
    stage_half(Ab + 64,                         &As[1][0],    tid);
    stage_half(Ab + (size_t)128 * KK + 64,      &As[1][8192], tid);
    stage_half(Wb + 64,                         &Bs[1][0],    tid);
    stage_half(Wb + (size_t)128 * KK + 64,      &Bs[1][8192], tid);
    asm volatile("s_waitcnt vmcnt(8)" ::: "memory");   // tile0 landed
    BAR();

    const int arow = wr * 128 + fr;   // + m*16
    const int brow = wc * 64  + fr;   // + n*16

    for (int it = 0; it < NITER; ++it) {
        const bool pf = (it + 1 < NITER);
        const int kt0 = 2 * it;
        const f16* Ac = &As[0][0]; const f16* Bc = &Bs[0][0];
        const f16* Ad = &As[1][0]; const f16* Bd = &Bs[1][0];
        f16x8 a0[8], b0[4], a1[8], b1[4];

        // ===== ph1: read buf0 k0 (12 b128); MFMA k0 m0-3
#pragma unroll
        for (int m = 0; m < 8; ++m) a0[m] = rd(Ac, arow + m * 16, fc);
#pragma unroll
        for (int n = 0; n < 4; ++n) b0[n] = rd(Bc, brow + n * 16, fc);
        BAR();
        __builtin_amdgcn_s_setprio(1);
#pragma unroll
        for (int m = 0; m < 4; ++m)
#pragma unroll
            for (int n = 0; n < 4; ++n)
                acc[m][n] = __builtin_amdgcn_mfma_f32_16x16x32_f16(a0[m], b0[n], acc[m][n], 0, 0, 0);
        __builtin_amdgcn_s_setprio(0);
        BAR();

        // ===== ph2: read buf0 k1; MFMA k0 m4-7
#pragma unroll
        for (int m = 0; m < 8; ++m) a1[m] = rd(Ac, arow + m * 16, 4 + fc);
#pragma unroll
        for (int n = 0; n < 4; ++n) b1[n] = rd(Bc, brow + n * 16, 4 + fc);
        BAR();
        __builtin_amdgcn_s_setprio(1);
#pragma unroll
        for (int m = 0; m < 4; ++m)
#pragma unroll
            for (int n = 0; n < 4; ++n)
                acc[4 + m][n] = __builtin_amdgcn_mfma_f32_16x16x32_f16(a0[4 + m], b0[n], acc[4 + m][n], 0, 0, 0);
        __builtin_amdgcn_s_setprio(0);
        BAR();

        // ===== ph3: stage buf0 A-H0 (tile kt0+2); MFMA k1 m0-3
        if (pf) stage_half(Ab + (size_t)(kt0 + 2) * BK, &As[0][0], tid);
        BAR();
        __builtin_amdgcn_s_setprio(1);
#pragma unroll
        for (int m = 0; m < 4; ++m)
#pragma unroll
            for (int n = 0; n < 4; ++n)
                acc[m][n] = __builtin_amdgcn_mfma_f32_16x16x32_f16(a1[m], b1[n], acc[m][n], 0, 0, 0);
        __builtin_amdgcn_s_setprio(0);
        BAR();

        // ===== ph4: stage buf0 A-H1; vmcnt; MFMA k1 m4-7
        if (pf) {
            stage_half(Ab + (size_t)128 * KK + (size_t)(kt0 + 2) * BK, &As[0][8192], tid);
            asm volatile("s_waitcnt vmcnt(4)" ::: "memory");   // buf1 tile kt0+1 landed
        } else {
            asm volatile("s_waitcnt vmcnt(0)" ::: "memory");
        }
        BAR();
        __builtin_amdgcn_s_setprio(1);
#pragma unroll
        for (int m = 0; m < 4; ++m)
#pragma unroll
            for (int n = 0; n < 4; ++n)
                acc[4 + m][n] = __builtin_amdgcn_mfma_f32_16x16x32_f16(a1[4 + m], b1[n], acc[4 + m][n], 0, 0, 0);
        __builtin_amdgcn_s_setprio(0);
        BAR();

        // ===== ph5: read buf1 k0; stage buf0 B-H0; MFMA(buf1) k0 m0-3
#pragma unroll
        for (int m = 0; m < 8; ++m) a0[m] = rd(Ad, arow + m * 16, fc);
#pragma unroll
        for (int n = 0; n < 4; ++n) b0[n] = rd(Bd, brow + n * 16, fc);
        if (pf) stage_half(Wb + (size_t)(kt0 + 2) * BK, &Bs[0][0], tid);
        BAR();
        __builtin_amdgcn_s_setprio(1);
#pragma unroll
        for (int m = 0; m < 4; ++m)
#pragma unroll
            for (int n = 0; n < 4; ++n)
                acc[m][n] = __builtin_amdgcn_mfma_f32_16x16x32_f16(a0[m], b0[n], acc[m][n], 0, 0, 0);
        __builtin_amdgcn_s_setprio(0);
        BAR();

        // ===== ph6: read buf1 k1; stage buf0 B-H1; MFMA k0 m4-7
#pragma unroll
        for (int m = 0; m < 8; ++m) a1[m] = rd(Ad, arow + m * 16, 4 + fc);
#pragma unroll
        for (int n = 0; n < 4; ++n) b1[n] = rd(Bd, brow + n * 16, 4 + fc);
        if (pf) stage_half(Wb + (size_t)128 * KK + (size_t)(kt0 + 2) * BK, &Bs[0][8192], tid);
        BAR();
        __builtin_amdgcn_s_setprio(1);
#pragma unroll
        for (int m = 0; m < 4; ++m)
#pragma unroll
            for (int n = 0; n < 4; ++n)
                acc[4 + m][n] = __builtin_amdgcn_mfma_f32_16x16x32_f16(a0[4 + m], b0[n], acc[4 + m][n], 0, 0, 0);
        __builtin_amdgcn_s_setprio(0);
        BAR();

        // ===== ph7: stage buf1 A-H0 + A-H1 (tile kt0+3); MFMA k1 m0-3
        if (pf) {
            stage_half(Ab + (size_t)(kt0 + 3) * BK,                      &As[1][0],    tid);
            stage_half(Ab + (size_t)128 * KK + (size_t)(kt0 + 3) * BK,   &As[1][8192], tid);
        }
        BAR();
        __builtin_amdgcn_s_setprio(1);
#pragma unroll
        for (int m = 0; m < 4; ++m)
#pragma unroll
            for (int n = 0; n < 4; ++n)
                acc[m][n] = __builtin_amdgcn_mfma_f32_16x16x32_f16(a1[m], b1[n], acc[m][n], 0, 0, 0);
        __builtin_amdgcn_s_setprio(0);
        BAR();

        // ===== ph8: stage buf1 B-H0 + B-H1; vmcnt; MFMA k1 m4-7
        if (pf) {
            stage_half(Wb + (size_t)(kt0 + 3) * BK,                      &Bs[1][0],    tid);
            stage_half(Wb + (size_t)128 * KK + (size_t)(kt0 + 3) * BK,   &Bs[1][8192], tid);
            asm volatile("s_waitcnt vmcnt(8)" ::: "memory");   // buf0 tile kt0+2 landed
        } else {
            asm volatile("s_waitcnt vmcnt(0)" ::: "memory");
        }
        BAR();
        __builtin_amdgcn_s_setprio(1);
#pragma unroll
        for (int m = 0; m < 4; ++m)
#pragma unroll
            for (int n = 0; n < 4; ++n)
                acc[4 + m][n] = __builtin_amdgcn_mfma_f32_16x16x32_f16(a1[4 + m], b1[n], acc[4 + m][n], 0, 0, 0);
        __builtin_amdgcn_s_setprio(0);
        BAR();
    }

    // epilogue: bias + tanh, store f16 (round-2 proven order: mi outer, ni, q)
#pragma unroll
    for (int mi = 0; mi < 8; ++mi) {
        const int r0 = tm + wr * 128 + mi * 16 + (fc << 2);
#pragma unroll
        for (int ni = 0; ni < 4; ++ni) {
            const int c = tn + wc * 64 + ni * 16 + fr;
            const float bv = bias[c];
#pragma unroll
            for (int q = 0; q < 4; ++q) {
                float z = acc[mi][ni][q] + bv;
                C[(size_t)(r0 + q) * NN + c] = (f16)tanhf(z);
            }
        }
    }
}

// ---------------- head: out[m] = sum_d h[m][d]*hw[d] + hb ----------------

__global__ void head_k(const f16* __restrict__ h, const float* __restrict__ hw,
                       const float* __restrict__ hb, float* __restrict__ out) {
    const int row  = blockIdx.x * 4 + (threadIdx.x >> 6);
    const int lane = threadIdx.x & 63;
    const f16* hr = h + (size_t)row * DD;
    float s = 0.f;
#pragma unroll
    for (int j = 0; j < DD / 64; ++j) {
        int d = lane + j * 64;
        s += (float)hr[d] * hw[d];
    }
#pragma unroll
    for (int o = 32; o > 0; o >>= 1) s += __shfl_down(s, o, 64);
    if (lane == 0) out[row] = s + hb[0];
}

// ---------------- launch ----------------

extern "C" void kernel_launch(void* const* d_in, const int* in_sizes, int n_in,
                              void* d_out, int out_size, void* d_ws, size_t ws_size,
                              hipStream_t stream) {
    const float* x    = (const float*)d_in[0];
    const float* Alog = (const float*)d_in[1];
    const float* Wls  = (const float*)d_in[2];
    const float* bls  = (const float*)d_in[3];
    const float* hw   = (const float*)d_in[4];
    const float* hb   = (const float*)d_in[5];
    float* out = (float*)d_out;

    char* ws = (char*)d_ws;
    const size_t hbytes = (size_t)MM * DD * sizeof(f16);   // 128 MiB
    f16* h0 = (f16*)ws;
    f16* h1 = (f16*)(ws + hbytes);
    char* scratch = ws + 2 * hbytes;
    float* carry = (float*)scratch;                         // 8 MiB, scan phase only
    f16*   wf    = (f16*)scratch;                           // 8 MiB, reused after scan

    // 1. scan (chunked, 3 passes)
    scan_pass1<<<(NCHUNK * BD) / 256, 256, 0, stream>>>(x, Alog, h0, carry);
    scan_pass2<<<BD / 256, 256, 0, stream>>>(Alog, carry);
    scan_pass3<<<(NCHUNK * BD) / 256, 256, 0, stream>>>(Alog, carry, h0);

    // 2. weights fp32 -> fp16 (reuses carry region; stream-ordered after pass3)
    cvt_w<<<(NLAYERS * DD * DD / 4) / 256, 256, 0, stream>>>(Wls, wf, NLAYERS * DD * DD);

    // 3. four layers, ping-pong (1-D grid of 1024 blocks, swizzles inside kernel)
    dim3 grid((MM / BM) * (NN / BN)), blk(512);
    gemm_tanh<<<grid, blk, 0, stream>>>(h0, wf + 0 * (DD * DD), bls + 0 * DD, h1);
    gemm_tanh<<<grid, blk, 0, stream>>>(h1, wf + 1 * (DD * DD), bls + 1 * DD, h0);
    gemm_tanh<<<grid, blk, 0, stream>>>(h0, wf + 2 * (DD * DD), bls + 2 * DD, h1);
    gemm_tanh<<<grid, blk, 0, stream>>>(h1, wf + 3 * (DD * DD), bls + 3 * DD, h0);

    // 4. head
    head_k<<<MM / 4, 256, 0, stream>>>(h0, hw, hb, out);
}

// Round 5
// 781.300 us; speedup vs baseline: 1.2360x; 1.0580x over previous
//
#include <hip/hip_runtime.h>
#include <cstdint>
#include <cstddef>

// Problem constants
#define LSEQ 2048
#define BB   32
#define DD   1024
#define NLAYERS 4
#define MM   (LSEQ*BB)      // 65536 rows
#define BD   (BB*DD)        // 32768
#define CHUNK 32
#define NCHUNK (LSEQ/CHUNK) // 64

typedef _Float16 f16;
typedef __attribute__((ext_vector_type(8))) _Float16 f16x8;
typedef __attribute__((ext_vector_type(4))) float f32x4;

// ---------------- scan: h[t] = a*h[t-1] + x[t], a = exp(A_log[d]) ----------------

__global__ void scan_pass1(const float* __restrict__ x, const float* __restrict__ Alog,
                           f16* __restrict__ h, float* __restrict__ carry) {
    int tid = blockIdx.x * blockDim.x + threadIdx.x;   // 2M threads
    int bd  = tid & (BD - 1);
    int c   = tid >> 15;                               // chunk id
    float a = expf(Alog[bd & (DD - 1)]);
    size_t base = (size_t)c * CHUNK * BD + bd;
    float hv = 0.f;
#pragma unroll
    for (int i = 0; i < CHUNK; ++i) {
        hv = a * hv + x[base + (size_t)i * BD];
        h[base + (size_t)i * BD] = (f16)hv;
    }
    carry[c * BD + bd] = hv;
}

__global__ void scan_pass2(const float* __restrict__ Alog, float* __restrict__ carry) {
    int bd = blockIdx.x * blockDim.x + threadIdx.x;    // 32768 threads
    float d32 = expf((float)CHUNK * Alog[bd & (DD - 1)]);  // a^CHUNK
    float cin = 0.f;
    for (int c = 0; c < NCHUNK; ++c) {
        float co = carry[c * BD + bd];
        carry[c * BD + bd] = cin;       // exclusive carry-in
        cin = d32 * cin + co;
    }
}

__global__ void scan_pass3(const float* __restrict__ Alog, const float* __restrict__ carry,
                           f16* __restrict__ h) {
    int tid = blockIdx.x * blockDim.x + threadIdx.x;
    int bd  = tid & (BD - 1);
    int c   = tid >> 15;
    float a   = expf(Alog[bd & (DD - 1)]);
    float cin = carry[c * BD + bd];
    size_t base = (size_t)c * CHUNK * BD + bd;
    float p = a;
#pragma unroll
    for (int i = 0; i < CHUNK; ++i) {
        size_t idx = base + (size_t)i * BD;
        float hv = (float)h[idx] + p * cin;
        h[idx] = (f16)hv;
        p *= a;
    }
}

// ---------------- fp32 -> fp16 weight conversion ----------------

__global__ void cvt_w(const float* __restrict__ w, f16* __restrict__ o, int n) {
    int i = (blockIdx.x * blockDim.x + threadIdx.x) * 4;
    if (i + 3 < n) {
        float4 v = *(const float4*)&w[i];
        o[i + 0] = (f16)v.x; o[i + 1] = (f16)v.y;
        o[i + 2] = (f16)v.z; o[i + 3] = (f16)v.w;
    }
}

// ---------------- GEMM + bias + tanh: 4-phase / 6-barrier schedule ----------------
// C[m][n] = tanh(sum_k A[m][k]*W[n][k] + b[n])
// Tile 256x256, BK=64, 2 K-tiles/iter (buf0=even, buf1=odd), 4 phases/iter,
// 32 MFMA (16x16x32 f16) per cluster. 512 thr = 8 waves (2Mx4N), wave 128x64.
// LDS 128 KiB. Occupancy is register-capped (acc=128 AGPR) at 2 waves/SIMD,
// so barrier count + in-wave read/MFMA overlap are the levers:
//   P1: read all 24 buf0 frags (k0-group first -> compiler waits lgkmcnt(12)
//       before k0 MFMA, the 12 k1 reads fly under the cluster); MFMA k0;
//       lgkmcnt(0); BAR  (buf0 reads retired block-wide -> safe to overwrite)
//   P2: stage tile+2 -> buf0; MFMA k1; vmcnt(8); BAR (tile+1 landed for P3)
//   P3/P4: mirror on buf1 (stage tile+3, vmcnt(8) -> tile+2 landed for next P1)
// Never vmcnt(0) in main loop (counted queue: exactly 8 in flight at checks).
// T2: chunk ^= (row&7) swizzle, inverse-swz global src, linear gload_lds dest.
// T5: setprio around MFMA clusters. T1: XCD-chunked block swizzle.

#define BM 256
#define BN 256
#define BK 64
#define KK 1024
#define NN 1024
#define NKTILE (KK / BK)     // 16
#define NITER  (NKTILE / 2)  // 8

__device__ __forceinline__ void gload_lds16(const void* g, void* l) {
    __builtin_amdgcn_global_load_lds((const __attribute__((address_space(1))) unsigned int*)g,
                                     (__attribute__((address_space(3))) unsigned int*)l,
                                     16, 0, 0);
}

// stage one half-tile: 128 rows x 64 f16 = 16 KiB, 2 loads/thread.
__device__ __forceinline__ void stage_half(const f16* __restrict__ gbase, f16* region, int tid) {
#pragma unroll
    for (int j = 0; j < 2; ++j) {
        int s = tid + j * 512;               // 16B slot 0..1023
        int r = s >> 3;                      // local row 0..127
        int c = (s & 7) ^ (r & 7);           // inverse-swizzled source chunk
        gload_lds16(gbase + (size_t)r * KK + c * 8, region + (size_t)s * 8);
    }
}

// stage a full 256x64 tile (A or W half-pair): 4 loads/thread
__device__ __forceinline__ void stage_tile(const f16* __restrict__ gA, const f16* __restrict__ gW,
                                           f16* As, f16* Bs, int tid) {
    stage_half(gA,                    As,        tid);
    stage_half(gA + (size_t)128 * KK, As + 8192, tid);
    stage_half(gW,                    Bs,        tid);
    stage_half(gW + (size_t)128 * KK, Bs + 8192, tid);
}

// swizzled fragment read from a [256][64] f16 tile
__device__ __forceinline__ f16x8 rd(const f16* base, int row, int chunk) {
    int c = chunk ^ (row & 7);
    return *(const f16x8*)(base + row * 64 + c * 8);
}

__device__ __forceinline__ float tanh_fast(float z) {
    // tanh(z) = 1 - 2/(e^{2z}+1); branchless, handles +-inf limits correctly.
    float e = __expf(2.f * z);
    return 1.f - 2.f / (e + 1.f);
}

#define BAR() do { __builtin_amdgcn_sched_barrier(0); __builtin_amdgcn_s_barrier(); \
                   __builtin_amdgcn_sched_barrier(0); } while (0)

__global__ __launch_bounds__(512, 2) void gemm_tanh(const f16* __restrict__ A,
                                                    const f16* __restrict__ W,
                                                    const float* __restrict__ bias,
                                                    f16* __restrict__ C) {
    __shared__ f16 As[2][BM * BK];   // 2 x 32 KiB
    __shared__ f16 Bs[2][BN * BK];   // 2 x 32 KiB

    const int tid  = threadIdx.x;
    const int lane = tid & 63;
    const int wid  = tid >> 6;        // 0..7
    const int wr   = wid >> 2;        // 0..1  (M half)
    const int wc   = wid & 3;         // 0..3  (N quarter)

    // T1: XCD-chunked bijective swizzle (nwg=1024, %8==0)
    const int cpx = gridDim.x >> 3;
    const int lin = ((int)blockIdx.x & 7) * cpx + ((int)blockIdx.x >> 3);
    const int tm  = (lin >> 2) * BM;
    const int tn  = (lin & 3) * BN;

    const f16* Ab = A + (size_t)tm * KK;
    const f16* Wb = W + (size_t)tn * KK;

    const int fr = lane & 15;         // fragment row within 16
    const int fc = lane >> 4;         // 16B k-chunk 0..3 within a 32-k step

    f32x4 acc[8][4];
#pragma unroll
    for (int i = 0; i < 8; ++i)
#pragma unroll
        for (int j = 0; j < 4; ++j)
            acc[i][j] = (f32x4){0.f, 0.f, 0.f, 0.f};

    // prologue: tile0 -> buf0, tile1 -> buf1 (16 loads/thread in flight)
    stage_tile(Ab,      Wb,      &As[0][0], &Bs[0][0], tid);
    stage_tile(Ab + 64, Wb + 64, &As[1][0], &Bs[1][0], tid);
    asm volatile("s_waitcnt vmcnt(8)" ::: "memory");   // tile0 landed
    BAR();

    const int arow = wr * 128 + fr;   // + m*16
    const int brow = wc * 64  + fr;   // + n*16

    for (int it = 0; it < NITER; ++it) {
        const bool pf = (it + 1 < NITER);
        const int kt0 = 2 * it;
        const f16* Ac = &As[0][0]; const f16* Bc = &Bs[0][0];
        const f16* Ad = &As[1][0]; const f16* Bd = &Bs[1][0];
        f16x8 a0[8], b0[4], a1[8], b1[4];

        // ===== P1: read buf0 (k0 group first, then k1); BAR; MFMA k0; lgkm0; BAR
#pragma unroll
        for (int m = 0; m < 8; ++m) a0[m] = rd(Ac, arow + m * 16, fc);
#pragma unroll
        for (int n = 0; n < 4; ++n) b0[n] = rd(Bc, brow + n * 16, fc);
#pragma unroll
        for (int m = 0; m < 8; ++m) a1[m] = rd(Ac, arow + m * 16, 4 + fc);
#pragma unroll
        for (int n = 0; n < 4; ++n) b1[n] = rd(Bc, brow + n * 16, 4 + fc);
        BAR();
        __builtin_amdgcn_s_setprio(1);
#pragma unroll
        for (int m = 0; m < 8; ++m)
#pragma unroll
            for (int n = 0; n < 4; ++n)
                acc[m][n] = __builtin_amdgcn_mfma_f32_16x16x32_f16(a0[m], b0[n], acc[m][n], 0, 0, 0);
        __builtin_amdgcn_s_setprio(0);
        asm volatile("s_waitcnt lgkmcnt(0)" ::: "memory");   // all buf0 reads retired
        BAR();

        // ===== P2: stage tile kt0+2 -> buf0; MFMA k1; vmcnt(8); BAR
        if (pf) stage_tile(Ab + (size_t)(kt0 + 2) * BK, Wb + (size_t)(kt0 + 2) * BK,
                           &As[0][0], &Bs[0][0], tid);
        __builtin_amdgcn_s_setprio(1);
#pragma unroll
        for (int m = 0; m < 8; ++m)
#pragma unroll
            for (int n = 0; n < 4; ++n)
                acc[m][n] = __builtin_amdgcn_mfma_f32_16x16x32_f16(a1[m], b1[n], acc[m][n], 0, 0, 0);
        __builtin_amdgcn_s_setprio(0);
        if (pf) asm volatile("s_waitcnt vmcnt(8)" ::: "memory");   // tile kt0+1 landed
        else    asm volatile("s_waitcnt vmcnt(0)" ::: "memory");
        BAR();

        // ===== P3: read buf1; BAR; MFMA k0; lgkm0; BAR
#pragma unroll
        for (int m = 0; m < 8; ++m) a0[m] = rd(Ad, arow + m * 16, fc);
#pragma unroll
        for (int n = 0; n < 4; ++n) b0[n] = rd(Bd, brow + n * 16, fc);
#pragma unroll
        for (int m = 0; m < 8; ++m) a1[m] = rd(Ad, arow + m * 16, 4 + fc);
#pragma unroll
        for (int n = 0; n < 4; ++n) b1[n] = rd(Bd, brow + n * 16, 4 + fc);
        BAR();
        __builtin_amdgcn_s_setprio(1);
#pragma unroll
        for (int m = 0; m < 8; ++m)
#pragma unroll
            for (int n = 0; n < 4; ++n)
                acc[m][n] = __builtin_amdgcn_mfma_f32_16x16x32_f16(a0[m], b0[n], acc[m][n], 0, 0, 0);
        __builtin_amdgcn_s_setprio(0);
        asm volatile("s_waitcnt lgkmcnt(0)" ::: "memory");   // all buf1 reads retired
        BAR();

        // ===== P4: stage tile kt0+3 -> buf1; MFMA k1; vmcnt(8); BAR
        if (pf) stage_tile(Ab + (size_t)(kt0 + 3) * BK, Wb + (size_t)(kt0 + 3) * BK,
                           &As[1][0], &Bs[1][0], tid);
        __builtin_amdgcn_s_setprio(1);
#pragma unroll
        for (int m = 0; m < 8; ++m)
#pragma unroll
            for (int n = 0; n < 4; ++n)
                acc[m][n] = __builtin_amdgcn_mfma_f32_16x16x32_f16(a1[m], b1[n], acc[m][n], 0, 0, 0);
        __builtin_amdgcn_s_setprio(0);
        if (pf) asm volatile("s_waitcnt vmcnt(8)" ::: "memory");   // tile kt0+2 landed
        else    asm volatile("s_waitcnt vmcnt(0)" ::: "memory");
        BAR();
    }

    // epilogue: bias + fast tanh, store f16 (mi outer: row-major store order)
#pragma unroll
    for (int mi = 0; mi < 8; ++mi) {
        const int r0 = tm + wr * 128 + mi * 16 + (fc << 2);
#pragma unroll
        for (int ni = 0; ni < 4; ++ni) {
            const int c = tn + wc * 64 + ni * 16 + fr;
            const float bv = bias[c];
#pragma unroll
            for (int q = 0; q < 4; ++q) {
                float z = acc[mi][ni][q] + bv;
                C[(size_t)(r0 + q) * NN + c] = (f16)tanh_fast(z);
            }
        }
    }
}

// ---------------- head: out[m] = sum_d h[m][d]*hw[d] + hb ----------------

__global__ void head_k(const f16* __restrict__ h, const float* __restrict__ hw,
                       const float* __restrict__ hb, float* __restrict__ out) {
    const int row  = blockIdx.x * 4 + (threadIdx.x >> 6);
    const int lane = threadIdx.x & 63;
    const f16* hr = h + (size_t)row * DD;
    float s = 0.f;
#pragma unroll
    for (int j = 0; j < DD / 64; ++j) {
        int d = lane + j * 64;
        s += (float)hr[d] * hw[d];
    }
#pragma unroll
    for (int o = 32; o > 0; o >>= 1) s += __shfl_down(s, o, 64);
    if (lane == 0) out[row] = s + hb[0];
}

// ---------------- launch ----------------

extern "C" void kernel_launch(void* const* d_in, const int* in_sizes, int n_in,
                              void* d_out, int out_size, void* d_ws, size_t ws_size,
                              hipStream_t stream) {
    const float* x    = (const float*)d_in[0];
    const float* Alog = (const float*)d_in[1];
    const float* Wls  = (const float*)d_in[2];
    const float* bls  = (const float*)d_in[3];
    const float* hw   = (const float*)d_in[4];
    const float* hb   = (const float*)d_in[5];
    float* out = (float*)d_out;

    char* ws = (char*)d_ws;
    const size_t hbytes = (size_t)MM * DD * sizeof(f16);   // 128 MiB
    f16* h0 = (f16*)ws;
    f16* h1 = (f16*)(ws + hbytes);
    char* scratch = ws + 2 * hbytes;
    float* carry = (float*)scratch;                         // 8 MiB, scan phase only
    f16*   wf    = (f16*)scratch;                           // 8 MiB, reused after scan

    // 1. scan (chunked, 3 passes)
    scan_pass1<<<(NCHUNK * BD) / 256, 256, 0, stream>>>(x, Alog, h0, carry);
    scan_pass2<<<BD / 256, 256, 0, stream>>>(Alog, carry);
    scan_pass3<<<(NCHUNK * BD) / 256, 256, 0, stream>>>(Alog, carry, h0);

    // 2. weights fp32 -> fp16 (reuses carry region; stream-ordered after pass3)
    cvt_w<<<(NLAYERS * DD * DD / 4) / 256, 256, 0, stream>>>(Wls, wf, NLAYERS * DD * DD);

    // 3. four layers, ping-pong (1-D grid of 1024 blocks, swizzles inside kernel)
    dim3 grid((MM / BM) * (NN / BN)), blk(512);
    gemm_tanh<<<grid, blk, 0, stream>>>(h0, wf + 0 * (DD * DD), bls + 0 * DD, h1);
    gemm_tanh<<<grid, blk, 0, stream>>>(h1, wf + 1 * (DD * DD), bls + 1 * DD, h0);
    gemm_tanh<<<grid, blk, 0, stream>>>(h0, wf + 2 * (DD * DD), bls + 2 * DD, h1);
    gemm_tanh<<<grid, blk, 0, stream>>>(h1, wf + 3 * (DD * DD), bls + 3 * DD, h0);

    // 4. head
    head_k<<<MM / 4, 256, 0, stream>>>(h0, hw, hb, out);
}